// Round 4
// baseline (84.728 us; speedup 1.0000x reference)
//
#include <hip/hip_runtime.h>
#include <math.h>

#define S_LEN 2048
#define D_DIM 256
#define WIN 33
#define HALF 16
#define PT_STRIDE 72   // shorts; 144 B rows -> 2-way bank aliasing (free)

typedef __attribute__((ext_vector_type(8))) short short8_t;  // 8 bf16 MFMA frag
typedef __attribute__((ext_vector_type(4))) float f32x4;

__device__ inline unsigned short f32_to_bf16(float f) {
    unsigned u = __float_as_uint(f);
    return (unsigned short)((u + 0x7fffu + ((u >> 16) & 1u)) >> 16);  // RNE
}

// Pack two f32 -> packed bf16x2 with round-half-away: one v_perm + two adds.
__device__ inline unsigned pack2_bf16(float lo, float hi) {
    unsigned a = __float_as_uint(lo) + 0x8000u;
    unsigned b = __float_as_uint(hi) + 0x8000u;
    // dst = (b & 0xFFFF0000) | (a >> 16)
    return __builtin_amdgcn_perm(b, a, 0x07060302);
}

__device__ inline short8_t pack_bf16x8(float4 x, float4 y) {
    union { unsigned u[4]; short8_t s; } r;
    r.u[0] = pack2_bf16(x.x, x.y);
    r.u[1] = pack2_bf16(x.z, x.w);
    r.u[2] = pack2_bf16(y.x, y.y);
    r.u[3] = pack2_bf16(y.z, y.w);
    return r.s;
}

// Block = 16 query rows, 128 threads = 2 waves.
// Wave 0: QK^T (global->reg bf16 frags), in-register softmax, p_attn store,
//         P -> small LDS slab.
// Both waves: preload ALL PV V-fragments to registers BEFORE the barrier
// (V independent of P -> overlaps wave 0's QK), then PV; wave h handles
// output dims [128h, 128h+128).
__global__ __launch_bounds__(128) void local_attn_wv(
    const float* __restrict__ q,
    const float* __restrict__ k,
    const float* __restrict__ v,
    const int*   __restrict__ mask,
    float* __restrict__ out_v,   // [B*S*D]
    float* __restrict__ out_p)   // [B*S*WIN]
{
    __shared__ __align__(16) unsigned short Pt[16 * PT_STRIDE];  // 2.3 KB

    const int t    = threadIdx.x;
    const int lane = t & 63;
    const int h    = t >> 6;          // wave id: 0 or 1
    const int l15  = lane & 15;
    const int q4   = lane >> 4;

    // XCD-contiguous tile swizzle: XCD x (round-robin bid%8) gets tiles
    // [x*64, x*64+64) -> its K/V halo stripe (~1 MB) stays in its own L2.
    const int bid  = blockIdx.x;              // 0..511
    const int tile = ((bid & 7) << 6) | (bid >> 3);
    const int b    = tile >> 7;               // 128 tiles per batch
    const int s0   = (tile & 127) << 4;       // first query row (in batch)

    const float* qb = q + ((size_t)b * S_LEN + s0) * D_DIM;
    const float* kb = k + (size_t)b * S_LEN * D_DIM;
    const float* vb = v + (size_t)b * S_LEN * D_DIM;

    if (h == 0) {
        // ---- per-lane span columns: 3 col-tiles of 16 (span = 48) ----
        int  krow[3]; bool mv[3];
#pragma unroll
        for (int ct = 0; ct < 3; ++ct) {
            const int kv    = s0 - HALF + ct * 16 + l15;
            const bool valid = (kv >= 0) && (kv < S_LEN);
            const int kc    = min(max(kv, 0), S_LEN - 1);
            krow[ct] = kc;
            mv[ct]   = valid && (mask[b * S_LEN + kc] != 0);
        }
        // ---- Q A-fragments: A[m=l15][k=q4*8+j], 8 k-steps ----
        short8_t aq[8];
#pragma unroll
        for (int ks = 0; ks < 8; ++ks) {
            const float* p = qb + l15 * D_DIM + ks * 32 + q4 * 8;
            const float4 x = *(const float4*)p;
            const float4 y = *(const float4*)(p + 4);
            aq[ks] = pack_bf16x8(x, y);
        }
        // ---- QK^T: 3 col-tiles x 8 k-steps ----
        f32x4 acc[3];
        acc[0] = (f32x4){0.f,0.f,0.f,0.f};
        acc[1] = (f32x4){0.f,0.f,0.f,0.f};
        acc[2] = (f32x4){0.f,0.f,0.f,0.f};
#pragma unroll
        for (int ct = 0; ct < 3; ++ct) {
            const float* kr = kb + (size_t)krow[ct] * D_DIM;
#pragma unroll
            for (int ks = 0; ks < 8; ++ks) {
                const float* p = kr + ks * 32 + q4 * 8;
                const float4 x = *(const float4*)p;
                const float4 y = *(const float4*)(p + 4);
                const short8_t bk = pack_bf16x8(x, y);
                acc[ct] = __builtin_amdgcn_mfma_f32_16x16x32_bf16(aq[ks], bk, acc[ct], 0, 0, 0);
            }
        }
        // ---- band + mask (C layout: row m = q4*4+r, col c = ct*16+l15) ----
        float sv[3][4];
#pragma unroll
        for (int ct = 0; ct < 3; ++ct)
#pragma unroll
            for (int r = 0; r < 4; ++r) {
                const int m = q4 * 4 + r;
                const int c = ct * 16 + l15;
                const int j = c - m;                       // window offset
                const bool inband = (j >= 0) && (j < WIN);
                const float s = acc[ct][r] * 0.0625f;      // 1/sqrt(256)
                sv[ct][r] = inband ? (mv[ct] ? s : -1e10f) : -1e30f;
            }
        // ---- softmax per row r: reduce across the quad's 16 lanes ----
        float rmax[4], rinv[4];
#pragma unroll
        for (int r = 0; r < 4; ++r) {
            float m = fmaxf(fmaxf(sv[0][r], sv[1][r]), sv[2][r]);
            m = fmaxf(m, __shfl_xor(m, 1, 64));
            m = fmaxf(m, __shfl_xor(m, 2, 64));
            m = fmaxf(m, __shfl_xor(m, 4, 64));
            m = fmaxf(m, __shfl_xor(m, 8, 64));
            rmax[r] = m;
        }
#pragma unroll
        for (int ct = 0; ct < 3; ++ct)
#pragma unroll
            for (int r = 0; r < 4; ++r)
                sv[ct][r] = __expf(sv[ct][r] - rmax[r]);   // out-of-band -> 0
#pragma unroll
        for (int r = 0; r < 4; ++r) {
            float s = sv[0][r] + sv[1][r] + sv[2][r];
            s += __shfl_xor(s, 1, 64);
            s += __shfl_xor(s, 2, 64);
            s += __shfl_xor(s, 4, 64);
            s += __shfl_xor(s, 8, 64);
            rinv[r] = 1.0f / s;
        }
        // ---- P -> LDS (bf16) + p_attn store (f32, from registers) ----
#pragma unroll
        for (int ct = 0; ct < 3; ++ct)
#pragma unroll
            for (int r = 0; r < 4; ++r) {
                const int m = q4 * 4 + r;
                const int c = ct * 16 + l15;
                const float p = sv[ct][r] * rinv[r];
                Pt[m * PT_STRIDE + c] = f32_to_bf16(p);
                const int j = c - m;
                if (j >= 0 && j < WIN)
                    out_p[((size_t)(b * S_LEN + s0 + m)) * WIN + j] = p;
            }
        // zero-pad P columns 48..63 (ap[1] reads them; bv there is 0 too,
        // but 0*NaN-garbage must be avoided)
#pragma unroll
        for (int r = 0; r < 4; ++r)
            Pt[(q4 * 4 + r) * PT_STRIDE + 48 + l15] = 0;
    }

    // ---- PV V-fragment preload (BOTH waves, before the barrier) ----
    // B[k=ks*32+q4*8+j][n=nt*16+l15]; k >= 48 has P=0 -> zero frag, no load.
    short8_t bv[8][2];
    {
        const float* vrk0[8];
        const float* vrk1[8];
#pragma unroll
        for (int j = 0; j < 8; ++j) {
            const int g0 = q4 * 8 + j;
            const int g1 = 32 + q4 * 8 + j;
            const int kv0 = min(max(s0 - HALF + g0, 0), S_LEN - 1);
            const int kv1 = min(max(s0 - HALF + g1, 0), S_LEN - 1);
            vrk0[j] = vb + (size_t)kv0 * D_DIM + h * 128;
            vrk1[j] = vb + (size_t)kv1 * D_DIM + h * 128;
        }
        const bool act1 = (q4 < 2);      // ks=1 frags with real k < 48
        const short8_t zfrag = {0,0,0,0,0,0,0,0};
#pragma unroll
        for (int nt = 0; nt < 8; ++nt) {
            const int d = nt * 16 + l15;
            float4 x, y;
            x.x = vrk0[0][d]; x.y = vrk0[1][d]; x.z = vrk0[2][d]; x.w = vrk0[3][d];
            y.x = vrk0[4][d]; y.y = vrk0[5][d]; y.z = vrk0[6][d]; y.w = vrk0[7][d];
            bv[nt][0] = pack_bf16x8(x, y);
            if (act1) {
                x.x = vrk1[0][d]; x.y = vrk1[1][d]; x.z = vrk1[2][d]; x.w = vrk1[3][d];
                y.x = vrk1[4][d]; y.y = vrk1[5][d]; y.z = vrk1[6][d]; y.w = vrk1[7][d];
                bv[nt][1] = pack_bf16x8(x, y);
            } else {
                bv[nt][1] = zfrag;
            }
        }
    }
    __syncthreads();

    // ---------------- PV: out(16 x 128) for this wave's D-half --------------
    short8_t ap[2];
    ap[0] = *(const short8_t*)&Pt[l15 * PT_STRIDE + q4 * 8];
    ap[1] = *(const short8_t*)&Pt[l15 * PT_STRIDE + 32 + q4 * 8];

    f32x4 acc[8];
#pragma unroll
    for (int nt = 0; nt < 8; ++nt) acc[nt] = (f32x4){0.f,0.f,0.f,0.f};
#pragma unroll
    for (int nt = 0; nt < 8; ++nt) {
        acc[nt] = __builtin_amdgcn_mfma_f32_16x16x32_bf16(ap[0], bv[nt][0], acc[nt], 0, 0, 0);
        acc[nt] = __builtin_amdgcn_mfma_f32_16x16x32_bf16(ap[1], bv[nt][1], acc[nt], 0, 0, 0);
    }
    float* ob = out_v + ((size_t)b * S_LEN + s0) * D_DIM + h * 128;
#pragma unroll
    for (int nt = 0; nt < 8; ++nt)
#pragma unroll
        for (int r = 0; r < 4; ++r)
            ob[(size_t)(q4 * 4 + r) * D_DIM + nt * 16 + l15] = acc[nt][r];
}

extern "C" void kernel_launch(void* const* d_in, const int* in_sizes, int n_in,
                              void* d_out, int out_size, void* d_ws, size_t ws_size,
                              hipStream_t stream) {
    const float* q    = (const float*)d_in[0];
    const float* k    = (const float*)d_in[1];
    const float* v    = (const float*)d_in[2];
    const int*   mask = (const int*)d_in[3];

    const int B = 4;
    float* out_v = (float*)d_out;
    float* out_p = (float*)d_out + (size_t)B * S_LEN * D_DIM;

    const int blocks = B * (S_LEN / 16);    // 512 blocks of 128 threads
    local_attn_wv<<<blocks, 128, 0, stream>>>(q, k, v, mask, out_v, out_p);
}